// Round 1
// baseline (1535.549 us; speedup 1.0000x reference)
//
#include <hip/hip_runtime.h>
#include <math.h>

#define BB 8
#define SS 64
#define LLN 64
#define DD 768
#define NBK 8
#define BLK 96
#define LH 33              // L/2+1
#define NROW (BB*SS*LLN)   // 32768

__device__ __forceinline__ constexpr int brev6(int x) {
  return ((x & 1) << 5) | ((x & 2) << 3) | ((x & 4) << 1) |
         ((x & 8) >> 1) | ((x & 16) >> 3) | ((x & 32) >> 5);
}

// In-register 64-point radix-2 DIT FFT. Input must be loaded bit-reversed.
// sgn = -1 forward (e^{-i}), +1 inverse (e^{+i}). tw[k] = (cos, sin)(2*pi*k/64).
__device__ __forceinline__ void fft64_regs(float* re, float* im, const float2* tw, float sgn) {
#pragma unroll
  for (int st = 0; st < 6; ++st) {
    const int half = 1 << st;
    const int tstep = 32 >> st;
#pragma unroll
    for (int k0 = 0; k0 < 64; k0 += (2 << st)) {
#pragma unroll
      for (int j = 0; j < (1 << st); ++j) {
        const int ti = j * tstep;
        float2 w = tw[ti];
        const float wr = w.x, wi = sgn * w.y;
        const int a = k0 + j, b = k0 + j + half;
        const float tr = re[b] * wr - im[b] * wi;
        const float tq = re[b] * wi + im[b] * wr;
        re[b] = re[a] - tr; im[b] = im[a] - tq;
        re[a] = re[a] + tr; im[a] = im[a] + tq;
      }
    }
  }
}

__device__ __forceinline__ void fill_tw(float2* tw, int t) {
  float ang = 6.28318530717958647692f * (float)t * (1.0f / 64.0f);
  tw[t] = make_float2(cosf(ang), sinf(ang));
}

// K1: mask + LayerNorm over D. One block (256 thr) per row.
__global__ __launch_bounds__(256) void k1_ln(const float* __restrict__ x,
    const unsigned char* __restrict__ pad, const float* __restrict__ lnw,
    const float* __restrict__ lnb, float* __restrict__ xln) {
  const int row = blockIdx.x;
  const int t = threadIdx.x;
  const float padv = pad[row] ? 0.0f : 1.0f;
  const float* xr = x + (size_t)row * DD;
  float v0 = xr[t] * padv, v1 = xr[t + 256] * padv, v2 = xr[t + 512] * padv;
  float sum = v0 + v1 + v2;
  float ssq = v0 * v0 + v1 * v1 + v2 * v2;
#pragma unroll
  for (int m = 1; m < 64; m <<= 1) {
    sum += __shfl_xor(sum, m, 64);
    ssq += __shfl_xor(ssq, m, 64);
  }
  __shared__ float red[8];
  const int wid = t >> 6;
  if ((t & 63) == 0) { red[wid] = sum; red[4 + wid] = ssq; }
  __syncthreads();
  sum = red[0] + red[1] + red[2] + red[3];
  ssq = red[4] + red[5] + red[6] + red[7];
  const float mu = sum * (1.0f / 768.0f);
  const float var = ssq * (1.0f / 768.0f) - mu * mu;
  const float rs = rsqrtf(var + 1e-5f);
  float* o = xln + (size_t)row * DD;
  o[t]       = (v0 - mu) * rs * lnw[t]       + lnb[t];
  o[t + 256] = (v1 - mu) * rs * lnw[t + 256] + lnb[t + 256];
  o[t + 512] = (v2 - mu) * rs * lnw[t + 512] + lnb[t + 512];
}

// K2: forward rFFT along L. One thread per (b,s,d); writes bins 0..32 to A.
__global__ __launch_bounds__(64) void k2_rfft_l(const float* __restrict__ xln,
                                                float2* __restrict__ A) {
  const int dt = blockIdx.x, s = blockIdx.y, b = blockIdx.z;
  const int d = dt * 64 + threadIdx.x;
  __shared__ float2 tw[64];
  fill_tw(tw, threadIdx.x);
  __syncthreads();
  const float* src = xln + ((size_t)(b * SS + s) * LLN) * DD + d;
  float re[64], im[64];
#pragma unroll
  for (int j = 0; j < 64; ++j) {
    re[j] = src[(size_t)brev6(j) * DD];
    im[j] = 0.0f;
  }
  fft64_regs(re, im, tw, -1.0f);
  float2* dst = A + ((size_t)(b * SS + s) * LH) * DD + d;
#pragma unroll
  for (int k = 0; k < LH; ++k) dst[(size_t)k * DD] = make_float2(re[k], im[k]);
}

// K3/K5: complex FFT along S, in place. FWD=1: e^{-i} and *1/64 (ortho rfft2 done).
// FWD=0: e^{+i}, no scale (deferred to K6).
template <int FWD>
__global__ __launch_bounds__(64) void k3_fft_s(float2* __restrict__ A) {
  const int dt = blockIdx.x, lh = blockIdx.y, b = blockIdx.z;
  const int d = dt * 64 + threadIdx.x;
  __shared__ float2 tw[64];
  fill_tw(tw, threadIdx.x);
  __syncthreads();
  float2* base = A + (((size_t)b * SS) * LH + lh) * DD + d;
  const size_t stride = (size_t)LH * DD;
  float re[64], im[64];
#pragma unroll
  for (int j = 0; j < 64; ++j) {
    float2 v = base[(size_t)brev6(j) * stride];
    re[j] = v.x; im[j] = v.y;
  }
  fft64_regs(re, im, tw, FWD ? -1.0f : 1.0f);
  const float sc = FWD ? (1.0f / 64.0f) : 1.0f;
#pragma unroll
  for (int s2 = 0; s2 < 64; ++s2)
    base[(size_t)s2 * stride] = make_float2(re[s2] * sc, im[s2] * sc);
}

// K4: block-diagonal complex MLP + exact GELU + complex soft-shrink, in place.
// One 96-thread block per (k, lh, b); z tile (64 s-freqs x 96) staged in LDS.
__global__ __launch_bounds__(96) void k4_mlp(float2* __restrict__ A,
    const float* __restrict__ w1, const float* __restrict__ b1,
    const float* __restrict__ w2, const float* __restrict__ b2) {
  const int k = blockIdx.x, lh = blockIdx.y, b = blockIdx.z;
  const int j = threadIdx.x;  // 0..95
  __shared__ float2 zt[64][BLK];
  __shared__ float2 o1[4][BLK];
  float2* base = A + (((size_t)b * SS) * LH + lh) * DD + k * BLK;
  const size_t srow = (size_t)LH * DD;
  for (int s2 = 0; s2 < 64; ++s2) zt[s2][j] = base[(size_t)s2 * srow + j];
  __syncthreads();
  const float* w1r = w1 + (size_t)k * BLK * BLK;
  const float* w1i = w1 + ((size_t)NBK + k) * BLK * BLK;
  const float* w2r = w2 + (size_t)k * BLK * BLK;
  const float* w2i = w2 + ((size_t)NBK + k) * BLK * BLK;
  const float b1r = b1[k * BLK + j], b1i = b1[(NBK + k) * BLK + j];
  const float b2r = b2[k * BLK + j], b2i = b2[(NBK + k) * BLK + j];
  for (int g = 0; g < 16; ++g) {
    float a1r[4], a1i[4];
#pragma unroll
    for (int f = 0; f < 4; ++f) { a1r[f] = b1r; a1i[f] = b1i; }
#pragma unroll 2
    for (int i = 0; i < BLK; ++i) {
      const float wr = w1r[i * BLK + j], wi = w1i[i * BLK + j];
#pragma unroll
      for (int f = 0; f < 4; ++f) {
        const float2 z = zt[g * 4 + f][i];
        a1r[f] += z.x * wr - z.y * wi;
        a1i[f] += z.y * wr + z.x * wi;
      }
    }
#pragma unroll
    for (int f = 0; f < 4; ++f) {
      const float xr = a1r[f], xi = a1i[f];
      o1[f][j] = make_float2(
          0.5f * xr * (1.0f + erff(xr * 0.70710678118654752f)),
          0.5f * xi * (1.0f + erff(xi * 0.70710678118654752f)));
    }
    __syncthreads();
    float a2r[4], a2i[4];
#pragma unroll
    for (int f = 0; f < 4; ++f) { a2r[f] = b2r; a2i[f] = b2i; }
#pragma unroll 2
    for (int i = 0; i < BLK; ++i) {
      const float wr = w2r[i * BLK + j], wi = w2i[i * BLK + j];
#pragma unroll
      for (int f = 0; f < 4; ++f) {
        const float2 h = o1[f][i];
        a2r[f] += h.x * wr - h.y * wi;
        a2i[f] += h.y * wr + h.x * wi;
      }
    }
#pragma unroll
    for (int f = 0; f < 4; ++f) {
      const float r = a2r[f], q = a2i[f];
      const float mag = sqrtf(r * r + q * q);
      const float fac = fmaxf(mag - 0.01f, 0.0f) / (mag + 1e-9f);
      base[(size_t)(g * 4 + f) * srow + j] = make_float2(r * fac, q * fac);
    }
    __syncthreads();
  }
}

// K6: inverse rFFT along L (Hermitian mirror) + mask + residual combine.
__global__ __launch_bounds__(64) void k6_irfft_l(const float2* __restrict__ A,
    const float* __restrict__ xln, const unsigned char* __restrict__ pad,
    const float* __restrict__ gamma, float* __restrict__ out) {
  const int dt = blockIdx.x, s = blockIdx.y, b = blockIdx.z;
  const int d = dt * 64 + threadIdx.x;
  __shared__ float2 tw[64];
  fill_tw(tw, threadIdx.x);
  __syncthreads();
  const float2* src = A + ((size_t)(b * SS + s) * LH) * DD + d;
  float re[64], im[64];
#pragma unroll
  for (int jj = 0; jj < 64; ++jj) {
    const int k = brev6(jj);
    const int k2 = (k <= 32) ? k : 64 - k;
    float2 v = src[(size_t)k2 * DD];
    re[jj] = v.x;
    im[jj] = (k <= 32) ? v.y : -v.y;
  }
  fft64_regs(re, im, tw, 1.0f);
  const float g = gamma[d];
  const float* xsrc = xln + ((size_t)(b * SS + s) * LLN) * DD + d;
  float* odst = out + ((size_t)(b * SS + s) * LLN) * DD + d;
  const unsigned char* prow = pad + (b * SS + s) * LLN;
#pragma unroll
  for (int l = 0; l < 64; ++l) {
    float y = re[l] * (1.0f / 64.0f);
    y = prow[l] ? 0.0f : y;
    odst[(size_t)l * DD] = xsrc[(size_t)l * DD] + g * y;
  }
}

extern "C" void kernel_launch(void* const* d_in, const int* in_sizes, int n_in,
                              void* d_out, int out_size, void* d_ws, size_t ws_size,
                              hipStream_t stream) {
  const float* x = (const float*)d_in[0];
  const unsigned char* pad = (const unsigned char*)d_in[1];
  const float* lnw = (const float*)d_in[2];
  const float* lnb = (const float*)d_in[3];
  const float* gamma = (const float*)d_in[4];
  const float* w1 = (const float*)d_in[5];
  const float* b1 = (const float*)d_in[6];
  const float* w2 = (const float*)d_in[7];
  const float* b2 = (const float*)d_in[8];
  float* out = (float*)d_out;

  float* xln = (float*)d_ws;                                     // 25,165,824 floats
  float2* A = (float2*)((char*)d_ws + (size_t)NROW * DD * 4);    // 12,976,128 float2

  k1_ln<<<dim3(NROW), dim3(256), 0, stream>>>(x, pad, lnw, lnb, xln);
  k2_rfft_l<<<dim3(12, 64, 8), dim3(64), 0, stream>>>(xln, A);
  k3_fft_s<1><<<dim3(12, 33, 8), dim3(64), 0, stream>>>(A);
  k4_mlp<<<dim3(8, 33, 8), dim3(96), 0, stream>>>(A, w1, b1, w2, b2);
  k3_fft_s<0><<<dim3(12, 33, 8), dim3(64), 0, stream>>>(A);
  k6_irfft_l<<<dim3(12, 64, 8), dim3(64), 0, stream>>>(A, xln, pad, gamma, out);
}

// Round 4
// 524.513 us; speedup vs baseline: 2.9276x; 2.9276x over previous
//
#include <hip/hip_runtime.h>
#include <math.h>

#define BB 8
#define SS 64
#define LLN 64
#define DD 768
#define NBK 8
#define BLK 96
#define LH 33              // L/2+1
#define NROW (BB*SS*LLN)   // 32768
#define MTOT (BB*SS*LH)    // 16896 frequency rows
#define MT 128             // M-tile rows per block (16896 = 132*128)
#define NMB (MTOT/MT)      // 132
#define SWS 208            // sW row stride bytes (13*16)
#define SZS 400            // sZ row stride bytes (25*16)

typedef float float4v __attribute__((ext_vector_type(4)));
typedef short short8  __attribute__((ext_vector_type(8)));

__device__ __forceinline__ unsigned short f2bf(float f) {
  unsigned int u = __float_as_uint(f);
  u += 0x7fffu + ((u >> 16) & 1u);   // RNE
  return (unsigned short)(u >> 16);
}

__device__ __forceinline__ short8 neg8(short8 v) {
  union { short8 s; unsigned int u[4]; } x;
  x.s = v;
  x.u[0] ^= 0x80008000u; x.u[1] ^= 0x80008000u;
  x.u[2] ^= 0x80008000u; x.u[3] ^= 0x80008000u;
  return x.s;
}

// tanh-form GELU: x - x/(exp2(c(x))+1), c(x) = 2*log2e*0.7978845608*(1 + 0.044715 x^2)
__device__ __forceinline__ float gelu_f(float x) {
  float t = x * x;
  float c = fmaf(0.1029532797f, t, 2.3022090506f);
  float s = __builtin_amdgcn_exp2f(x * c);
  return x - x * __builtin_amdgcn_rcpf(s + 1.0f);
}

__device__ __forceinline__ constexpr int brev6(int x) {
  return ((x & 1) << 5) | ((x & 2) << 3) | ((x & 4) << 1) |
         ((x & 8) >> 1) | ((x & 16) >> 3) | ((x & 32) >> 5);
}

__device__ __forceinline__ void fft64_regs(float* re, float* im, const float2* tw, float sgn) {
#pragma unroll
  for (int st = 0; st < 6; ++st) {
    const int half = 1 << st;
    const int tstep = 32 >> st;
#pragma unroll
    for (int k0 = 0; k0 < 64; k0 += (2 << st)) {
#pragma unroll
      for (int j = 0; j < (1 << st); ++j) {
        const int ti = j * tstep;
        float2 w = tw[ti];
        const float wr = w.x, wi = sgn * w.y;
        const int a = k0 + j, b = k0 + j + half;
        const float tr = re[b] * wr - im[b] * wi;
        const float tq = re[b] * wi + im[b] * wr;
        re[b] = re[a] - tr; im[b] = im[a] - tq;
        re[a] = re[a] + tr; im[a] = im[a] + tq;
      }
    }
  }
}

__device__ __forceinline__ void fill_tw(float2* tw, int t) {
  float ang = 6.28318530717958647692f * (float)t * (1.0f / 64.0f);
  tw[t] = make_float2(cosf(ang), sinf(ang));
}

// K1: mask + LayerNorm over D. One block (256 thr) per row.
__global__ __launch_bounds__(256) void k1_ln(const float* __restrict__ x,
    const unsigned char* __restrict__ pad, const float* __restrict__ lnw,
    const float* __restrict__ lnb, float* __restrict__ xln) {
  const int row = blockIdx.x;
  const int t = threadIdx.x;
  const float padv = pad[row] ? 0.0f : 1.0f;
  const float* xr = x + (size_t)row * DD;
  float v0 = xr[t] * padv, v1 = xr[t + 256] * padv, v2 = xr[t + 512] * padv;
  float sum = v0 + v1 + v2;
  float ssq = v0 * v0 + v1 * v1 + v2 * v2;
#pragma unroll
  for (int m = 1; m < 64; m <<= 1) {
    sum += __shfl_xor(sum, m, 64);
    ssq += __shfl_xor(ssq, m, 64);
  }
  __shared__ float red[8];
  const int wid = t >> 6;
  if ((t & 63) == 0) { red[wid] = sum; red[4 + wid] = ssq; }
  __syncthreads();
  sum = red[0] + red[1] + red[2] + red[3];
  ssq = red[4] + red[5] + red[6] + red[7];
  const float mu = sum * (1.0f / 768.0f);
  const float var = ssq * (1.0f / 768.0f) - mu * mu;
  const float rs = rsqrtf(var + 1e-5f);
  float* o = xln + (size_t)row * DD;
  o[t]       = (v0 - mu) * rs * lnw[t]       + lnb[t];
  o[t + 256] = (v1 - mu) * rs * lnw[t + 256] + lnb[t + 256];
  o[t + 512] = (v2 - mu) * rs * lnw[t + 512] + lnb[t + 512];
}

// K2: forward rFFT along L.
__global__ __launch_bounds__(64) void k2_rfft_l(const float* __restrict__ xln,
                                                float2* __restrict__ A) {
  const int dt = blockIdx.x, s = blockIdx.y, b = blockIdx.z;
  const int d = dt * 64 + threadIdx.x;
  __shared__ float2 tw[64];
  fill_tw(tw, threadIdx.x);
  __syncthreads();
  const float* src = xln + ((size_t)(b * SS + s) * LLN) * DD + d;
  float re[64], im[64];
#pragma unroll
  for (int j = 0; j < 64; ++j) {
    re[j] = src[(size_t)brev6(j) * DD];
    im[j] = 0.0f;
  }
  fft64_regs(re, im, tw, -1.0f);
  float2* dst = A + ((size_t)(b * SS + s) * LH) * DD + d;
#pragma unroll
  for (int k = 0; k < LH; ++k) dst[(size_t)k * DD] = make_float2(re[k], im[k]);
}

// K3/K5: complex FFT along S, in place.
template <int FWD>
__global__ __launch_bounds__(64) void k3_fft_s(float2* __restrict__ A) {
  const int dt = blockIdx.x, lh = blockIdx.y, b = blockIdx.z;
  const int d = dt * 64 + threadIdx.x;
  __shared__ float2 tw[64];
  fill_tw(tw, threadIdx.x);
  __syncthreads();
  float2* base = A + (((size_t)b * SS) * LH + lh) * DD + d;
  const size_t stride = (size_t)LH * DD;
  float re[64], im[64];
#pragma unroll
  for (int j = 0; j < 64; ++j) {
    float2 v = base[(size_t)brev6(j) * stride];
    re[j] = v.x; im[j] = v.y;
  }
  fft64_regs(re, im, tw, FWD ? -1.0f : 1.0f);
  const float sc = FWD ? (1.0f / 64.0f) : 1.0f;
#pragma unroll
  for (int s2 = 0; s2 < 64; ++s2)
    base[(size_t)s2 * stride] = make_float2(re[s2] * sc, im[s2] * sc);
}

// K4: block-diagonal complex MLP via bf16 MFMA, in place on A.
// Block: 512 thr (8 waves = 4M x 2N), one 128-row M-tile x one k-block.
// LDS: padded strides (no swizzle): sW 4 mats x 96 rows x 208B; sZ 128 rows x 400B.
__global__ __launch_bounds__(512, 2) void k4_mfma(float2* __restrict__ A,
    const float* __restrict__ w1, const float* __restrict__ b1,
    const float* __restrict__ w2, const float* __restrict__ b2) {
  __shared__ __align__(16) char sW[4 * 96 * SWS];   // 79872 B: Wt[mat][n][k] bf16
  __shared__ __align__(16) char sZ[MT * SZS];       // 51200 B: Z/H [row][kk 0..191] bf16
  const int kb = blockIdx.y;
  const int m0 = blockIdx.x * MT;
  const int tid = threadIdx.x;
  const int lane = tid & 63;
  const int wid = tid >> 6;
  const int wm = wid >> 1;     // 0..3 : rows 32*wm .. +31
  const int wn = wid & 1;      // 0..1 : col-triples
  const int l15 = lane & 15;
  const int g = lane >> 4;

  // ---- stage weights: Wt[n][k] = W[k][n], bf16 ----
  {
    const float* srcs[4] = { w1 + (size_t)kb * 9216, w1 + (size_t)(8 + kb) * 9216,
                             w2 + (size_t)kb * 9216, w2 + (size_t)(8 + kb) * 9216 };
#pragma unroll
    for (int mat = 0; mat < 4; ++mat) {
      const float* s = srcs[mat];
      char* dstb = sW + mat * 96 * SWS;
      for (int it = 0; it < 18; ++it) {
        int e = tid + 512 * it;          // 0..9215
        int k = e / 96, n = e % 96;
        *(unsigned short*)(dstb + n * SWS + 2 * k) = f2bf(s[e]);
      }
    }
  }
  // ---- stage Z tile: rows m0..m0+127, chans kb*96..+95 -> [row][kk] (kk<96 re, >=96 im)
  {
    const float4* zb = (const float4*)(A + (size_t)m0 * DD + kb * BLK);
    for (int it = 0; it < 12; ++it) {
      int e = tid + 512 * it;            // 0..6143
      int r = e / 48, c4 = e % 48;       // float4 = channels 2c4, 2c4+1
      float4 v = zb[(size_t)r * (DD / 2) + c4];
      unsigned int pr = (unsigned int)f2bf(v.x) | ((unsigned int)f2bf(v.z) << 16);
      unsigned int pi = (unsigned int)f2bf(v.y) | ((unsigned int)f2bf(v.w) << 16);
      char* rowb = sZ + r * SZS;
      *(unsigned int*)(rowb + 4 * c4) = pr;
      *(unsigned int*)(rowb + 192 + 4 * c4) = pi;
    }
  }
  __syncthreads();

  float4v accR[2][3], accI[2][3];
#pragma unroll
  for (int m = 0; m < 2; ++m)
#pragma unroll
    for (int p = 0; p < 3; ++p) { accR[m][p] = (float4v)0.0f; accI[m][p] = (float4v)0.0f; }

  // ---- layer 1: H = GELU(Z * W1c + b1) ----
#pragma unroll
  for (int ks = 0; ks < 3; ++ks) {
    short8 ar[2], ai[2], ain[2];
#pragma unroll
    for (int m = 0; m < 2; ++m) {
      const char* rowb = sZ + (32 * wm + 16 * m + l15) * SZS;
      ar[m] = *(const short8*)(rowb + 64 * ks + 16 * g);
      ai[m] = *(const short8*)(rowb + 192 + 64 * ks + 16 * g);
      ain[m] = neg8(ai[m]);
    }
#pragma unroll
    for (int p = 0; p < 3; ++p) {
      const int n = (3 * wn + p) * 16 + l15;
      const int ko = 64 * ks + 16 * g;
      const short8 br = *(const short8*)(sW + 0 * 96 * SWS + n * SWS + ko);
      const short8 bi = *(const short8*)(sW + 1 * 96 * SWS + n * SWS + ko);
#pragma unroll
      for (int m = 0; m < 2; ++m) {
        accR[m][p] = __builtin_amdgcn_mfma_f32_16x16x32_bf16(ar[m],  br, accR[m][p], 0, 0, 0);
        accR[m][p] = __builtin_amdgcn_mfma_f32_16x16x32_bf16(ain[m], bi, accR[m][p], 0, 0, 0);
        accI[m][p] = __builtin_amdgcn_mfma_f32_16x16x32_bf16(ai[m],  br, accI[m][p], 0, 0, 0);
        accI[m][p] = __builtin_amdgcn_mfma_f32_16x16x32_bf16(ar[m],  bi, accI[m][p], 0, 0, 0);
      }
    }
  }
  // bias + GELU (registers only)
#pragma unroll
  for (int p = 0; p < 3; ++p) {
    const int col = (3 * wn + p) * 16 + l15;
    const float b1r = b1[kb * 96 + col];
    const float b1i = b1[768 + kb * 96 + col];
#pragma unroll
    for (int m = 0; m < 2; ++m)
#pragma unroll
      for (int r = 0; r < 4; ++r) {
        accR[m][p][r] = gelu_f(accR[m][p][r] + b1r);
        accI[m][p][r] = gelu_f(accI[m][p][r] + b1i);
      }
  }
  __syncthreads();   // all layer-1 LDS reads done before overwrite
  // write H (bf16) into sZ, same layout
#pragma unroll
  for (int m = 0; m < 2; ++m)
#pragma unroll
    for (int p = 0; p < 3; ++p) {
      const int col = (3 * wn + p) * 16 + l15;
#pragma unroll
      for (int r = 0; r < 4; ++r) {
        char* rowb = sZ + (32 * wm + 16 * m + 4 * g + r) * SZS;
        *(unsigned short*)(rowb + 2 * col)         = f2bf(accR[m][p][r]);
        *(unsigned short*)(rowb + 192 + 2 * col)   = f2bf(accI[m][p][r]);
      }
    }
  __syncthreads();

  // ---- layer 2: O = H * W2c + b2, then complex soft-shrink ----
#pragma unroll
  for (int m = 0; m < 2; ++m)
#pragma unroll
    for (int p = 0; p < 3; ++p) { accR[m][p] = (float4v)0.0f; accI[m][p] = (float4v)0.0f; }
#pragma unroll
  for (int ks = 0; ks < 3; ++ks) {
    short8 hr[2], hi[2], hin[2];
#pragma unroll
    for (int m = 0; m < 2; ++m) {
      const char* rowb = sZ + (32 * wm + 16 * m + l15) * SZS;
      hr[m] = *(const short8*)(rowb + 64 * ks + 16 * g);
      hi[m] = *(const short8*)(rowb + 192 + 64 * ks + 16 * g);
      hin[m] = neg8(hi[m]);
    }
#pragma unroll
    for (int p = 0; p < 3; ++p) {
      const int n = (3 * wn + p) * 16 + l15;
      const int ko = 64 * ks + 16 * g;
      const short8 br = *(const short8*)(sW + 2 * 96 * SWS + n * SWS + ko);
      const short8 bi = *(const short8*)(sW + 3 * 96 * SWS + n * SWS + ko);
#pragma unroll
      for (int m = 0; m < 2; ++m) {
        accR[m][p] = __builtin_amdgcn_mfma_f32_16x16x32_bf16(hr[m],  br, accR[m][p], 0, 0, 0);
        accR[m][p] = __builtin_amdgcn_mfma_f32_16x16x32_bf16(hin[m], bi, accR[m][p], 0, 0, 0);
        accI[m][p] = __builtin_amdgcn_mfma_f32_16x16x32_bf16(hi[m],  br, accI[m][p], 0, 0, 0);
        accI[m][p] = __builtin_amdgcn_mfma_f32_16x16x32_bf16(hr[m],  bi, accI[m][p], 0, 0, 0);
      }
    }
  }
  // bias + soft-shrink + write back to A
#pragma unroll
  for (int p = 0; p < 3; ++p) {
    const int col = (3 * wn + p) * 16 + l15;
    const float b2r = b2[kb * 96 + col];
    const float b2i = b2[768 + kb * 96 + col];
#pragma unroll
    for (int m = 0; m < 2; ++m)
#pragma unroll
      for (int r = 0; r < 4; ++r) {
        const float xv = accR[m][p][r] + b2r;
        const float yv = accI[m][p][r] + b2i;
        const float mag = sqrtf(xv * xv + yv * yv);
        const float fac = fmaxf(mag - 0.01f, 0.0f) / (mag + 1e-9f);
        const int row = m0 + 32 * wm + 16 * m + 4 * g + r;
        A[(size_t)row * DD + kb * BLK + col] = make_float2(xv * fac, yv * fac);
      }
  }
}

// K6: inverse rFFT along L (Hermitian mirror) + mask + residual combine.
__global__ __launch_bounds__(64) void k6_irfft_l(const float2* __restrict__ A,
    const float* __restrict__ xln, const unsigned char* __restrict__ pad,
    const float* __restrict__ gamma, float* __restrict__ out) {
  const int dt = blockIdx.x, s = blockIdx.y, b = blockIdx.z;
  const int d = dt * 64 + threadIdx.x;
  __shared__ float2 tw[64];
  fill_tw(tw, threadIdx.x);
  __syncthreads();
  const float2* src = A + ((size_t)(b * SS + s) * LH) * DD + d;
  float re[64], im[64];
#pragma unroll
  for (int jj = 0; jj < 64; ++jj) {
    const int k = brev6(jj);
    const int k2 = (k <= 32) ? k : 64 - k;
    float2 v = src[(size_t)k2 * DD];
    re[jj] = v.x;
    im[jj] = (k <= 32) ? v.y : -v.y;
  }
  fft64_regs(re, im, tw, 1.0f);
  const float g = gamma[d];
  const float* xsrc = xln + ((size_t)(b * SS + s) * LLN) * DD + d;
  float* odst = out + ((size_t)(b * SS + s) * LLN) * DD + d;
  const unsigned char* prow = pad + (b * SS + s) * LLN;
#pragma unroll
  for (int l = 0; l < 64; ++l) {
    float y = re[l] * (1.0f / 64.0f);
    y = prow[l] ? 0.0f : y;
    odst[(size_t)l * DD] = xsrc[(size_t)l * DD] + g * y;
  }
}

extern "C" void kernel_launch(void* const* d_in, const int* in_sizes, int n_in,
                              void* d_out, int out_size, void* d_ws, size_t ws_size,
                              hipStream_t stream) {
  const float* x = (const float*)d_in[0];
  const unsigned char* pad = (const unsigned char*)d_in[1];
  const float* lnw = (const float*)d_in[2];
  const float* lnb = (const float*)d_in[3];
  const float* gamma = (const float*)d_in[4];
  const float* w1 = (const float*)d_in[5];
  const float* b1 = (const float*)d_in[6];
  const float* w2 = (const float*)d_in[7];
  const float* b2 = (const float*)d_in[8];
  float* out = (float*)d_out;

  float* xln = (float*)d_ws;
  float2* A = (float2*)((char*)d_ws + (size_t)NROW * DD * 4);

  k1_ln<<<dim3(NROW), dim3(256), 0, stream>>>(x, pad, lnw, lnb, xln);
  k2_rfft_l<<<dim3(12, 64, 8), dim3(64), 0, stream>>>(xln, A);
  k3_fft_s<1><<<dim3(12, 33, 8), dim3(64), 0, stream>>>(A);
  k4_mfma<<<dim3(NMB, 8), dim3(512), 0, stream>>>(A, w1, b1, w2, b2);
  k3_fft_s<0><<<dim3(12, 33, 8), dim3(64), 0, stream>>>(A);
  k6_irfft_l<<<dim3(12, 64, 8), dim3(64), 0, stream>>>(A, xln, pad, gamma, out);
}

// Round 5
// 439.412 us; speedup vs baseline: 3.4946x; 1.1937x over previous
//
#include <hip/hip_runtime.h>
#include <math.h>

#define BB 8
#define SS 64
#define LLN 64
#define DD 768
#define NBK 8
#define BLK 96
#define LH 33              // L/2+1
#define NROW (BB*SS*LLN)   // 32768
#define SWS 208            // W row stride bytes (13*16)
#define SFS 144            // F / transposed-tile row stride bytes (9*16)

typedef float float4v __attribute__((ext_vector_type(4)));
typedef short short8  __attribute__((ext_vector_type(8)));

__device__ __forceinline__ unsigned short f2bf(float f) {
  unsigned int u = __float_as_uint(f);
  u += 0x7fffu + ((u >> 16) & 1u);   // RNE
  return (unsigned short)(u >> 16);
}

__device__ __forceinline__ short8 neg8(short8 v) {
  union { short8 s; unsigned int u[4]; } x;
  x.s = v;
  x.u[0] ^= 0x80008000u; x.u[1] ^= 0x80008000u;
  x.u[2] ^= 0x80008000u; x.u[3] ^= 0x80008000u;
  return x.s;
}

// tanh-form GELU
__device__ __forceinline__ float gelu_f(float x) {
  float t = x * x;
  float c = fmaf(0.1029532797f, t, 2.3022090506f);
  float s = __builtin_amdgcn_exp2f(x * c);
  return x - x * __builtin_amdgcn_rcpf(s + 1.0f);
}

__device__ __forceinline__ constexpr int brev6(int x) {
  return ((x & 1) << 5) | ((x & 2) << 3) | ((x & 4) << 1) |
         ((x & 8) >> 1) | ((x & 16) >> 3) | ((x & 32) >> 5);
}

__device__ __forceinline__ void fft64_regs(float* re, float* im, const float2* tw, float sgn) {
#pragma unroll
  for (int st = 0; st < 6; ++st) {
    const int half = 1 << st;
    const int tstep = 32 >> st;
#pragma unroll
    for (int k0 = 0; k0 < 64; k0 += (2 << st)) {
#pragma unroll
      for (int j = 0; j < (1 << st); ++j) {
        const int ti = j * tstep;
        float2 w = tw[ti];
        const float wr = w.x, wi = sgn * w.y;
        const int a = k0 + j, b = k0 + j + half;
        const float tr = re[b] * wr - im[b] * wi;
        const float tq = re[b] * wi + im[b] * wr;
        re[b] = re[a] - tr; im[b] = im[a] - tq;
        re[a] = re[a] + tr; im[a] = im[a] + tq;
      }
    }
  }
}

__device__ __forceinline__ void fill_tw(float2* tw, int t) {
  float ang = 6.28318530717958647692f * (float)t * (1.0f / 64.0f);
  tw[t] = make_float2(cosf(ang), sinf(ang));
}

// K1: mask + LayerNorm over D. One block (256 thr) per row.
__global__ __launch_bounds__(256) void k1_ln(const float* __restrict__ x,
    const unsigned char* __restrict__ pad, const float* __restrict__ lnw,
    const float* __restrict__ lnb, float* __restrict__ xln) {
  const int row = blockIdx.x;
  const int t = threadIdx.x;
  const float padv = pad[row] ? 0.0f : 1.0f;
  const float* xr = x + (size_t)row * DD;
  float v0 = xr[t] * padv, v1 = xr[t + 256] * padv, v2 = xr[t + 512] * padv;
  float sum = v0 + v1 + v2;
  float ssq = v0 * v0 + v1 * v1 + v2 * v2;
#pragma unroll
  for (int m = 1; m < 64; m <<= 1) {
    sum += __shfl_xor(sum, m, 64);
    ssq += __shfl_xor(ssq, m, 64);
  }
  __shared__ float red[8];
  const int wid = t >> 6;
  if ((t & 63) == 0) { red[wid] = sum; red[4 + wid] = ssq; }
  __syncthreads();
  sum = red[0] + red[1] + red[2] + red[3];
  ssq = red[4] + red[5] + red[6] + red[7];
  const float mu = sum * (1.0f / 768.0f);
  const float var = ssq * (1.0f / 768.0f) - mu * mu;
  const float rs = rsqrtf(var + 1e-5f);
  float* o = xln + (size_t)row * DD;
  o[t]       = (v0 - mu) * rs * lnw[t]       + lnb[t];
  o[t + 256] = (v1 - mu) * rs * lnw[t + 256] + lnb[t + 256];
  o[t + 512] = (v2 - mu) * rs * lnw[t + 512] + lnb[t + 512];
}

// K2: forward rFFT along L. 256 threads = 4 d-tiles per block.
__global__ __launch_bounds__(256) void k2_rfft_l(const float* __restrict__ xln,
                                                 float2* __restrict__ A) {
  const int s = blockIdx.y, b = blockIdx.z;
  const int d = blockIdx.x * 256 + threadIdx.x;
  __shared__ float2 tw[64];
  if (threadIdx.x < 64) fill_tw(tw, threadIdx.x);
  __syncthreads();
  const float* src = xln + ((size_t)(b * SS + s) * LLN) * DD + d;
  float re[64], im[64];
#pragma unroll
  for (int j = 0; j < 64; ++j) {
    re[j] = src[(size_t)brev6(j) * DD];
    im[j] = 0.0f;
  }
  fft64_regs(re, im, tw, -1.0f);
  float2* dst = A + ((size_t)(b * SS + s) * LH) * DD + d;
#pragma unroll
  for (int k = 0; k < LH; ++k) dst[(size_t)k * DD] = make_float2(re[k], im[k]);
}

// K345: fused {fwd S-DFT (x 1/64) -> complex MLP (GELU) -> soft-shrink -> inv S-DFT},
// all via bf16 MFMA. One block = (kb, lh, b): 96 channels x 64 s-points. 512 thr / 8 waves.
// Wave (wm = wid>>1, wn = wid&1): m-tile 16*wm, n-tiles 16*(3*wn+p), p=0..2.
__global__ __launch_bounds__(512) void k345(float2* __restrict__ A,
    const float* __restrict__ w1, const float* __restrict__ b1,
    const float* __restrict__ w2, const float* __restrict__ b2) {
  __shared__ __align__(16) char sW[4 * 96 * SWS];   // 79872: W1r,W1i,W2r,W2i [n][k]
  __shared__ __align__(16) char sF[2 * 64 * SFS];   // 18432: cos@0, sin@9216  [k][s]
  __shared__ __align__(16) char sBufA[27648];       // ZT r@0,i@13824  ->  H r@0,i@13312
  __shared__ __align__(16) char sBufB[27648];       // Z1 r@0,i@13312  ->  ZT2 r@0,i@13824
  const int kb = blockIdx.x, lh = blockIdx.y, b = blockIdx.z;
  const int tid = threadIdx.x;
  const int lane = tid & 63;
  const int wid = tid >> 6;
  const int wm = wid >> 1;
  const int wn = wid & 1;
  const int l15 = lane & 15;
  const int g = lane >> 4;

  // ---- stage weights [n][k] bf16 ----
  {
    const float* srcs[4] = { w1 + (size_t)kb * 9216, w1 + (size_t)(8 + kb) * 9216,
                             w2 + (size_t)kb * 9216, w2 + (size_t)(8 + kb) * 9216 };
#pragma unroll
    for (int mat = 0; mat < 4; ++mat) {
      const float* s = srcs[mat];
      char* dstb = sW + mat * 96 * SWS;
      for (int it = 0; it < 18; ++it) {
        int e = tid + 512 * it;
        int k = e / 96, n = e % 96;
        *(unsigned short*)(dstb + n * SWS + 2 * k) = f2bf(s[e]);
      }
    }
  }
  // ---- stage DFT matrix cos/sin[k][s] bf16 ----
  for (int it = 0; it < 8; ++it) {
    int idx = tid + 512 * it;
    int k = idx >> 6, s = idx & 63;
    int m = (k * s) & 63;
    float ang = (float)m * 0.0981747704246810387f;   // 2*pi/64
    *(unsigned short*)(sF + k * SFS + 2 * s) = f2bf(cosf(ang));
    *(unsigned short*)(sF + 9216 + k * SFS + 2 * s) = f2bf(sinf(ang));
  }
  // ---- stage Z transposed: ZT[ch][s] bf16 (r,i) ----
  {
    const float4* zb = (const float4*)A;
    const size_t rbase = ((size_t)(b * SS) * LH + lh) * (DD / 2) + kb * 48;
    for (int it = 0; it < 6; ++it) {
      int e = tid + 512 * it;              // 0..3071
      int s = e / 48, c4 = e % 48;
      float4 v = zb[rbase + (size_t)s * (LH * DD / 2) + c4];
      int ch0 = 2 * c4;
      *(unsigned short*)(sBufA + ch0 * SFS + 2 * s)               = f2bf(v.x);
      *(unsigned short*)(sBufA + 13824 + ch0 * SFS + 2 * s)       = f2bf(v.y);
      *(unsigned short*)(sBufA + (ch0 + 1) * SFS + 2 * s)         = f2bf(v.z);
      *(unsigned short*)(sBufA + 13824 + (ch0 + 1) * SFS + 2 * s) = f2bf(v.w);
    }
  }
  __syncthreads();

  float4v aR[3], aI[3];

  // ---- G1: fwd DFT:  Zh = (C - iS) Z / 64 ----
#pragma unroll
  for (int p = 0; p < 3; ++p) { aR[p] = (float4v)0.0f; aI[p] = (float4v)0.0f; }
#pragma unroll
  for (int ks = 0; ks < 2; ++ks) {
    const int ko = 64 * ks + 16 * g;
    const short8 fc = *(const short8*)(sF + (16 * wm + l15) * SFS + ko);
    const short8 fs = *(const short8*)(sF + 9216 + (16 * wm + l15) * SFS + ko);
    const short8 fsn = neg8(fs);
#pragma unroll
    for (int p = 0; p < 3; ++p) {
      const int ch = 16 * (3 * wn + p) + l15;
      const short8 zr = *(const short8*)(sBufA + ch * SFS + ko);
      const short8 zi = *(const short8*)(sBufA + 13824 + ch * SFS + ko);
      aR[p] = __builtin_amdgcn_mfma_f32_16x16x32_bf16(fc,  zr, aR[p], 0, 0, 0);
      aR[p] = __builtin_amdgcn_mfma_f32_16x16x32_bf16(fs,  zi, aR[p], 0, 0, 0);
      aI[p] = __builtin_amdgcn_mfma_f32_16x16x32_bf16(fc,  zi, aI[p], 0, 0, 0);
      aI[p] = __builtin_amdgcn_mfma_f32_16x16x32_bf16(fsn, zr, aI[p], 0, 0, 0);
    }
  }
  // write Z1[row][ch] = Zh * (1/64)
#pragma unroll
  for (int p = 0; p < 3; ++p) {
    const int ch = 16 * (3 * wn + p) + l15;
#pragma unroll
    for (int r = 0; r < 4; ++r) {
      const int row = 16 * wm + 4 * g + r;
      *(unsigned short*)(sBufB + row * SWS + 2 * ch)         = f2bf(aR[p][r] * 0.015625f);
      *(unsigned short*)(sBufB + 13312 + row * SWS + 2 * ch) = f2bf(aI[p][r] * 0.015625f);
    }
  }
  __syncthreads();

  // ---- G2: layer 1 + GELU ----
#pragma unroll
  for (int p = 0; p < 3; ++p) { aR[p] = (float4v)0.0f; aI[p] = (float4v)0.0f; }
#pragma unroll
  for (int ks = 0; ks < 3; ++ks) {
    const int ko = 64 * ks + 16 * g;
    const int row = 16 * wm + l15;
    const short8 ar = *(const short8*)(sBufB + row * SWS + ko);
    const short8 ai = *(const short8*)(sBufB + 13312 + row * SWS + ko);
    const short8 ain = neg8(ai);
#pragma unroll
    for (int p = 0; p < 3; ++p) {
      const int n = 16 * (3 * wn + p) + l15;
      const short8 br = *(const short8*)(sW + 0 * 96 * SWS + n * SWS + ko);
      const short8 bi = *(const short8*)(sW + 1 * 96 * SWS + n * SWS + ko);
      aR[p] = __builtin_amdgcn_mfma_f32_16x16x32_bf16(ar,  br, aR[p], 0, 0, 0);
      aR[p] = __builtin_amdgcn_mfma_f32_16x16x32_bf16(ain, bi, aR[p], 0, 0, 0);
      aI[p] = __builtin_amdgcn_mfma_f32_16x16x32_bf16(ai,  br, aI[p], 0, 0, 0);
      aI[p] = __builtin_amdgcn_mfma_f32_16x16x32_bf16(ar,  bi, aI[p], 0, 0, 0);
    }
  }
#pragma unroll
  for (int p = 0; p < 3; ++p) {
    const int col = 16 * (3 * wn + p) + l15;
    const float b1r = b1[kb * 96 + col];
    const float b1i = b1[768 + kb * 96 + col];
#pragma unroll
    for (int r = 0; r < 4; ++r) {
      const float hr = gelu_f(aR[p][r] + b1r);
      const float hi = gelu_f(aI[p][r] + b1i);
      const int row = 16 * wm + 4 * g + r;
      *(unsigned short*)(sBufA + row * SWS + 2 * col)         = f2bf(hr);
      *(unsigned short*)(sBufA + 13312 + row * SWS + 2 * col) = f2bf(hi);
    }
  }
  __syncthreads();

  // ---- G3: layer 2 + bias + soft-shrink, store transposed ZT2[ch][k] ----
#pragma unroll
  for (int p = 0; p < 3; ++p) { aR[p] = (float4v)0.0f; aI[p] = (float4v)0.0f; }
#pragma unroll
  for (int ks = 0; ks < 3; ++ks) {
    const int ko = 64 * ks + 16 * g;
    const int row = 16 * wm + l15;
    const short8 hr = *(const short8*)(sBufA + row * SWS + ko);
    const short8 hi = *(const short8*)(sBufA + 13312 + row * SWS + ko);
    const short8 hin = neg8(hi);
#pragma unroll
    for (int p = 0; p < 3; ++p) {
      const int n = 16 * (3 * wn + p) + l15;
      const short8 br = *(const short8*)(sW + 2 * 96 * SWS + n * SWS + ko);
      const short8 bi = *(const short8*)(sW + 3 * 96 * SWS + n * SWS + ko);
      aR[p] = __builtin_amdgcn_mfma_f32_16x16x32_bf16(hr,  br, aR[p], 0, 0, 0);
      aR[p] = __builtin_amdgcn_mfma_f32_16x16x32_bf16(hin, bi, aR[p], 0, 0, 0);
      aI[p] = __builtin_amdgcn_mfma_f32_16x16x32_bf16(hi,  br, aI[p], 0, 0, 0);
      aI[p] = __builtin_amdgcn_mfma_f32_16x16x32_bf16(hr,  bi, aI[p], 0, 0, 0);
    }
  }
  __syncthreads();   // all G2 reads of sBufB done before ZT2 overwrite
#pragma unroll
  for (int p = 0; p < 3; ++p) {
    const int col = 16 * (3 * wn + p) + l15;
    const float b2r = b2[kb * 96 + col];
    const float b2i = b2[768 + kb * 96 + col];
#pragma unroll
    for (int r = 0; r < 4; ++r) {
      const float xv = aR[p][r] + b2r;
      const float yv = aI[p][r] + b2i;
      const float mag = sqrtf(xv * xv + yv * yv);
      const float fac = fmaxf(mag - 0.01f, 0.0f) / (mag + 1e-9f);
      const int row = 16 * wm + 4 * g + r;
      *(unsigned short*)(sBufB + col * SFS + 2 * row)         = f2bf(xv * fac);
      *(unsigned short*)(sBufB + 13824 + col * SFS + 2 * row) = f2bf(yv * fac);
    }
  }
  __syncthreads();

  // ---- G4: inverse DFT:  O = (C + iS) Z2, write fp32 ----
#pragma unroll
  for (int p = 0; p < 3; ++p) { aR[p] = (float4v)0.0f; aI[p] = (float4v)0.0f; }
#pragma unroll
  for (int ks = 0; ks < 2; ++ks) {
    const int ko = 64 * ks + 16 * g;
    const short8 fc = *(const short8*)(sF + (16 * wm + l15) * SFS + ko);
    const short8 fs = *(const short8*)(sF + 9216 + (16 * wm + l15) * SFS + ko);
    const short8 fsn = neg8(fs);
#pragma unroll
    for (int p = 0; p < 3; ++p) {
      const int ch = 16 * (3 * wn + p) + l15;
      const short8 zr = *(const short8*)(sBufB + ch * SFS + ko);
      const short8 zi = *(const short8*)(sBufB + 13824 + ch * SFS + ko);
      aR[p] = __builtin_amdgcn_mfma_f32_16x16x32_bf16(fc,  zr, aR[p], 0, 0, 0);
      aR[p] = __builtin_amdgcn_mfma_f32_16x16x32_bf16(fsn, zi, aR[p], 0, 0, 0);
      aI[p] = __builtin_amdgcn_mfma_f32_16x16x32_bf16(fc,  zi, aI[p], 0, 0, 0);
      aI[p] = __builtin_amdgcn_mfma_f32_16x16x32_bf16(fs,  zr, aI[p], 0, 0, 0);
    }
  }
#pragma unroll
  for (int p = 0; p < 3; ++p) {
    const int ch = 16 * (3 * wn + p) + l15;
#pragma unroll
    for (int r = 0; r < 4; ++r) {
      const int s = 16 * wm + 4 * g + r;
      A[((size_t)(b * SS + s) * LH + lh) * DD + kb * BLK + ch] =
          make_float2(aR[p][r], aI[p][r]);
    }
  }
}

// K6: inverse rFFT along L (Hermitian mirror) + mask + residual. 256 thr = 4 d-tiles.
__global__ __launch_bounds__(256) void k6_irfft_l(const float2* __restrict__ A,
    const float* __restrict__ xln, const unsigned char* __restrict__ pad,
    const float* __restrict__ gamma, float* __restrict__ out) {
  const int s = blockIdx.y, b = blockIdx.z;
  const int d = blockIdx.x * 256 + threadIdx.x;
  __shared__ float2 tw[64];
  if (threadIdx.x < 64) fill_tw(tw, threadIdx.x);
  __syncthreads();
  const float2* src = A + ((size_t)(b * SS + s) * LH) * DD + d;
  float re[64], im[64];
#pragma unroll
  for (int jj = 0; jj < 64; ++jj) {
    const int k = brev6(jj);
    const int k2 = (k <= 32) ? k : 64 - k;
    float2 v = src[(size_t)k2 * DD];
    re[jj] = v.x;
    im[jj] = (k <= 32) ? v.y : -v.y;
  }
  fft64_regs(re, im, tw, 1.0f);
  const float g = gamma[d];
  const float* xsrc = xln + ((size_t)(b * SS + s) * LLN) * DD + d;
  float* odst = out + ((size_t)(b * SS + s) * LLN) * DD + d;
  const unsigned char* prow = pad + (b * SS + s) * LLN;
#pragma unroll
  for (int l = 0; l < 64; ++l) {
    float y = re[l] * (1.0f / 64.0f);
    y = prow[l] ? 0.0f : y;
    odst[(size_t)l * DD] = xsrc[(size_t)l * DD] + g * y;
  }
}

extern "C" void kernel_launch(void* const* d_in, const int* in_sizes, int n_in,
                              void* d_out, int out_size, void* d_ws, size_t ws_size,
                              hipStream_t stream) {
  const float* x = (const float*)d_in[0];
  const unsigned char* pad = (const unsigned char*)d_in[1];
  const float* lnw = (const float*)d_in[2];
  const float* lnb = (const float*)d_in[3];
  const float* gamma = (const float*)d_in[4];
  const float* w1 = (const float*)d_in[5];
  const float* b1 = (const float*)d_in[6];
  const float* w2 = (const float*)d_in[7];
  const float* b2 = (const float*)d_in[8];
  float* out = (float*)d_out;

  float* xln = (float*)d_ws;
  float2* A = (float2*)((char*)d_ws + (size_t)NROW * DD * 4);

  k1_ln<<<dim3(NROW), dim3(256), 0, stream>>>(x, pad, lnw, lnb, xln);
  k2_rfft_l<<<dim3(3, 64, 8), dim3(256), 0, stream>>>(xln, A);
  k345<<<dim3(8, 33, 8), dim3(512), 0, stream>>>(A, w1, b1, w2, b2);
  k6_irfft_l<<<dim3(3, 64, 8), dim3(256), 0, stream>>>(A, xln, pad, gamma, out);
}